// Round 1
// baseline (688.126 us; speedup 1.0000x reference)
//
#include <hip/hip_runtime.h>

#define S_DIM 256
#define R_DIM 384
#define C_DIM 256
#define H_DIM 8
#define AC_DIM 32
#define HC_DIM 256
#define M_DIM (S_DIM * R_DIM)  // 98304 rows, m = r*S + s

typedef __attribute__((ext_vector_type(8))) short short8;
typedef __attribute__((ext_vector_type(4))) float floatx4;

__device__ __forceinline__ unsigned short f2bf(float f) {
  unsigned u = __float_as_uint(f);
  u += 0x7FFFu + ((u >> 16) & 1u);  // round-to-nearest-even
  return (unsigned short)(u >> 16);
}
__device__ __forceinline__ float bf2f(unsigned short s) {
  return __uint_as_float(((unsigned)s) << 16);
}
__device__ __forceinline__ unsigned packbf2(float a, float b) {
  return (unsigned)f2bf(a) | ((unsigned)f2bf(b) << 16);
}

// async global->LDS, 16B per lane; LDS dest = wave-uniform base + lane*16
#define GLD_LDS16(gp, lp)                                                      \
  __builtin_amdgcn_global_load_lds(                                            \
      (const __attribute__((address_space(1))) unsigned int*)(gp),             \
      (__attribute__((address_space(3))) unsigned int*)(lp), 16, 0, 0)

// ---------------------------------------------------------------------------
// Kernel A: weight pre-pass. Wt[n][k] bf16, n in [0,1280):
//   n<1024: {wq,wk,wv,wg}[k][n&255]; n>=1024: wo[k][n&255].
// 64x64 LDS transpose tiles.
// ---------------------------------------------------------------------------
__global__ __launch_bounds__(256) void wcat_kernel(
    const float* __restrict__ wq, const float* __restrict__ wk,
    const float* __restrict__ wv, const float* __restrict__ wg,
    const float* __restrict__ wo, unsigned short* __restrict__ wt) {
  __shared__ float tile[64][65];
  const int n0 = blockIdx.x * 64;  // 0..1216
  const int k0 = blockIdx.y * 64;
  const int wi = n0 >> 8;
  const float* src = (wi == 0) ? wq : (wi == 1) ? wk : (wi == 2) ? wv
                   : (wi == 3) ? wg : wo;
  const int col0 = n0 & 255;
  const int tx = threadIdx.x & 63;
  const int ty = threadIdx.x >> 6;
#pragma unroll
  for (int i = 0; i < 16; ++i) {
    int kl = ty + i * 4;
    tile[kl][tx] = src[(size_t)(k0 + kl) * 256 + col0 + tx];
  }
  __syncthreads();
#pragma unroll
  for (int i = 0; i < 16; ++i) {
    int nl = ty + i * 4;
    wt[(size_t)(n0 + nl) * 256 + k0 + tx] = f2bf(tile[tx][nl]);
  }
}

// ---------------------------------------------------------------------------
// Kernel B: fused LayerNorm -> bf16 x_ln in m-order (m = r*S + s).
// One wave per msa row p = s*R + r. float4 read, ushort4 write.
// ---------------------------------------------------------------------------
__global__ __launch_bounds__(256) void ln_kernel(
    const float* __restrict__ msa, const float* __restrict__ ln_g,
    const float* __restrict__ ln_b, unsigned short* __restrict__ xln) {
  const int p = blockIdx.x * 4 + (threadIdx.x >> 6);
  const int lane = threadIdx.x & 63;
  const float4 v = ((const float4*)(msa + (size_t)p * C_DIM))[lane];
  float s = v.x + v.y + v.z + v.w;
  float ss = v.x * v.x + v.y * v.y + v.z * v.z + v.w * v.w;
#pragma unroll
  for (int o = 1; o < 64; o <<= 1) {
    s += __shfl_xor(s, o);
    ss += __shfl_xor(ss, o);
  }
  const float mu = s * (1.0f / C_DIM);
  const float rstd = rsqrtf(ss * (1.0f / C_DIM) - mu * mu + 1e-5f);
  const float4 g = ((const float4*)ln_g)[lane];
  const float4 b = ((const float4*)ln_b)[lane];
  const int sq = p / R_DIM;          // s
  const int r = p - sq * R_DIM;      // r
  const size_t m = (size_t)r * S_DIM + sq;
  ushort4 o;
  o.x = f2bf((v.x - mu) * rstd * g.x + b.x);
  o.y = f2bf((v.y - mu) * rstd * g.y + b.y);
  o.z = f2bf((v.z - mu) * rstd * g.z + b.z);
  o.w = f2bf((v.w - mu) * rstd * g.w + b.w);
  *(ushort4*)(xln + m * C_DIM + lane * 4) = o;
}

// ---------------------------------------------------------------------------
// Kernel C: projection GEMM v2. C[m][n] = xln[m][k] * Wt[n][k].
// Full-K=256 A staged in LDS up-front (64KB, 8 chunks x 8 groups x 512),
// ONE __syncthreads total (no per-K-step barrier/vmcnt drain).
// B frags register-direct from global (L2-hot, <=512KB), double-buffered
// with static indexing. Chunked XCD swizzle: the 8 n-tiles of one m-tile
// land on the same XCD -> A-panel fetched once per XCD.
// Epilogue: n>>8 selects q(scale)/k/v/g(sigmoid+bg), bf16 stores.
// ---------------------------------------------------------------------------
__global__ __launch_bounds__(256) void proj_kernel(
    const unsigned short* __restrict__ xln, const unsigned short* __restrict__ wt,
    const float* __restrict__ bg, unsigned short* __restrict__ q_ws,
    unsigned short* __restrict__ k_ws, unsigned short* __restrict__ v_ws,
    unsigned short* __restrict__ g_ws) {
  __shared__ __align__(16) unsigned short As[8 * 8 * 512];  // 64 KB: [chunk][group][512]

  // chunked XCD swizzle: hw assigns block i -> XCD i%8; give XCD x the
  // contiguous original-range [x*768, (x+1)*768). 6144 % 8 == 0 -> bijective.
  const int bid = blockIdx.x;
  const int orig = (bid & 7) * 768 + (bid >> 3);
  const int n0 = (orig & 7) << 7;   // n-tile fastest: 8 consecutive origs share A-panel
  const int m0 = (orig >> 3) << 7;

  const int tid = threadIdx.x;
  const int wave = tid >> 6, lane = tid & 63;
  const int qd = lane >> 4, lm = lane & 15;
  const int wm = (wave & 1) * 64, wn = (wave >> 1) * 64;

  // ---- stage ALL of A (128 rows x 256 k) into LDS, 16 loads/wave ----
  const int ga0 = wave * 2, ga1 = wave * 2 + 1;
  const unsigned short* agp0 = xln + (size_t)(m0 + ga0 * 16 + lm) * 256 + qd * 8;
  const unsigned short* agp1 = xln + (size_t)(m0 + ga1 * 16 + lm) * 256 + qd * 8;
#pragma unroll
  for (int c = 0; c < 8; ++c) {
    GLD_LDS16(agp0 + c * 32, &As[(size_t)(c * 8 + ga0) * 512]);
    GLD_LDS16(agp1 + c * 32, &As[(size_t)(c * 8 + ga1) * 512]);
  }

  // ---- B row pointers (register-direct frags; same layout as old LDS path) ----
  const unsigned short* bp0 = wt + (size_t)(n0 + wn + 0 * 16 + lm) * 256 + qd * 8;
  const unsigned short* bp1 = wt + (size_t)(n0 + wn + 1 * 16 + lm) * 256 + qd * 8;
  const unsigned short* bp2 = wt + (size_t)(n0 + wn + 2 * 16 + lm) * 256 + qd * 8;
  const unsigned short* bp3 = wt + (size_t)(n0 + wn + 3 * 16 + lm) * 256 + qd * 8;

  floatx4 acc[4][4];
#pragma unroll
  for (int i = 0; i < 4; ++i)
#pragma unroll
    for (int j = 0; j < 4; ++j) acc[i][j] = (floatx4){0.f, 0.f, 0.f, 0.f};

  short8 bfr[2][4];
  bfr[0][0] = *(const short8*)(bp0);
  bfr[0][1] = *(const short8*)(bp1);
  bfr[0][2] = *(const short8*)(bp2);
  bfr[0][3] = *(const short8*)(bp3);

  __syncthreads();  // the ONLY barrier: drains the 16 A-stage loads

#pragma unroll
  for (int c = 0; c < 8; ++c) {
    if (c < 7) {  // prefetch next B chunk into the other (statically indexed) buffer
      bfr[(c + 1) & 1][0] = *(const short8*)(bp0 + (c + 1) * 32);
      bfr[(c + 1) & 1][1] = *(const short8*)(bp1 + (c + 1) * 32);
      bfr[(c + 1) & 1][2] = *(const short8*)(bp2 + (c + 1) * 32);
      bfr[(c + 1) & 1][3] = *(const short8*)(bp3 + (c + 1) * 32);
    }
    short8 af[4];
#pragma unroll
    for (int t = 0; t < 4; ++t)
      af[t] = *(const short8*)((const char*)As +
                               (size_t)(c * 8 + wm / 16 + t) * 1024 + lane * 16);
#pragma unroll
    for (int tm = 0; tm < 4; ++tm)
#pragma unroll
      for (int tn = 0; tn < 4; ++tn)
        acc[tm][tn] = __builtin_amdgcn_mfma_f32_16x16x32_bf16(
            af[tm], bfr[c & 1][tn], acc[tm][tn], 0, 0, 0);
  }

  const int wi = n0 >> 8;
  const int colbase = (n0 & 255) + wn;
#pragma unroll
  for (int tm = 0; tm < 4; ++tm)
#pragma unroll
    for (int tn = 0; tn < 4; ++tn)
#pragma unroll
      for (int rg = 0; rg < 4; ++rg) {
        const int m = m0 + wm + tm * 16 + qd * 4 + rg;
        const int col = colbase + tn * 16 + lm;
        const size_t off = (size_t)m * 256 + col;
        float val = acc[tm][tn][rg];
        if (wi == 0) {
          q_ws[off] = f2bf(val * 0.17677669529663689f);  // 1/sqrt(32)
        } else if (wi == 1) {
          k_ws[off] = f2bf(val);
        } else if (wi == 2) {
          v_ws[off] = f2bf(val);
        } else {
          g_ws[off] = f2bf(1.0f / (1.0f + __expf(-(val + bg[col]))));
        }
      }
}

// ---------------------------------------------------------------------------
// Kernel D: flash-style MFMA attention per (r, h) — unchanged.
// ---------------------------------------------------------------------------
#define PSTRIDE 40
#define VSTRIDE 264

__global__ __launch_bounds__(256) void attn_kernel(
    const unsigned short* __restrict__ q_ws, const unsigned short* __restrict__ k_ws,
    const unsigned short* __restrict__ v_ws, const unsigned short* __restrict__ g_ws,
    const float* __restrict__ mask, unsigned short* __restrict__ ctx_ws) {
  __shared__ __align__(16) unsigned short V_lds[32 * VSTRIDE];
  __shared__ __align__(16) unsigned short P_lds[4 * 16 * PSTRIDE];
  __shared__ float Bias[S_DIM];

  const int r = blockIdx.x;
  const int h = blockIdx.y;
  const int tid = threadIdx.x;
  const int wave = tid >> 6, lane = tid & 63;
  const int qd = lane >> 4, lm = lane & 15;
  const int qw = wave * 64;

  const size_t rS = (size_t)r * S_DIM;
  const int hb = h * AC_DIM;

  {
    const int s = tid;
    const unsigned short* vp = v_ws + (rS + s) * HC_DIM + hb;
    const int pos = (s & ~31) + ((s & 15) * 2) + ((s >> 4) & 1);
    uint4 u0 = *(const uint4*)(vp);
    uint4 u1 = *(const uint4*)(vp + 8);
    uint4 u2 = *(const uint4*)(vp + 16);
    uint4 u3 = *(const uint4*)(vp + 24);
    const unsigned w[16] = {u0.x, u0.y, u0.z, u0.w, u1.x, u1.y, u1.z, u1.w,
                            u2.x, u2.y, u2.z, u2.w, u3.x, u3.y, u3.z, u3.w};
#pragma unroll
    for (int d2 = 0; d2 < 16; ++d2) {
      V_lds[(d2 * 2 + 0) * VSTRIDE + pos] = (unsigned short)(w[d2] & 0xFFFF);
      V_lds[(d2 * 2 + 1) * VSTRIDE + pos] = (unsigned short)(w[d2] >> 16);
    }
    Bias[s] = 1e9f * (mask[(size_t)s * R_DIM + r] - 1.0f);
  }

  short8 qf[4];
#pragma unroll
  for (int qi = 0; qi < 4; ++qi)
    qf[qi] = *(const short8*)(q_ws + (rS + qw + qi * 16 + lm) * HC_DIM + hb + qd * 8);

  float m_st[4][4], l_st[4][4];
  floatx4 oacc[4][2];
#pragma unroll
  for (int qi = 0; qi < 4; ++qi) {
#pragma unroll
    for (int rg = 0; rg < 4; ++rg) {
      m_st[qi][rg] = -1e30f;
      l_st[qi][rg] = 0.0f;
    }
    oacc[qi][0] = (floatx4){0.f, 0.f, 0.f, 0.f};
    oacc[qi][1] = (floatx4){0.f, 0.f, 0.f, 0.f};
  }

  __syncthreads();

  unsigned short* Pw = &P_lds[wave * 16 * PSTRIDE];
  const floatx4 zero4 = (floatx4){0.f, 0.f, 0.f, 0.f};

  for (int ch = 0; ch < 8; ++ch) {
    const int kb = ch * 32;
    const float b0 = Bias[kb + lm];
    const float b1 = Bias[kb + 16 + lm];
    short8 kf0 = *(const short8*)(k_ws + (rS + kb + lm) * HC_DIM + hb + qd * 8);
    short8 kf1 = *(const short8*)(k_ws + (rS + kb + 16 + lm) * HC_DIM + hb + qd * 8);
    short8 vf0 = *(const short8*)&V_lds[lm * VSTRIDE + kb + qd * 8];
    short8 vf1 = *(const short8*)&V_lds[(16 + lm) * VSTRIDE + kb + qd * 8];

#pragma unroll
    for (int qi = 0; qi < 4; ++qi) {
      floatx4 s0 = __builtin_amdgcn_mfma_f32_16x16x32_bf16(qf[qi], kf0, zero4, 0, 0, 0);
      floatx4 s1 = __builtin_amdgcn_mfma_f32_16x16x32_bf16(qf[qi], kf1, zero4, 0, 0, 0);
      unsigned pw[4];
#pragma unroll
      for (int rg = 0; rg < 4; ++rg) {
        float a0 = s0[rg] + b0;
        float a1 = s1[rg] + b1;
        float t = fmaxf(a0, a1);
        t = fmaxf(t, __shfl_xor(t, 1));
        t = fmaxf(t, __shfl_xor(t, 2));
        t = fmaxf(t, __shfl_xor(t, 4));
        t = fmaxf(t, __shfl_xor(t, 8));
        float mold = m_st[qi][rg];
        float mnew = fmaxf(mold, t);
        float alpha = __expf(mold - mnew);
        float p0 = __expf(a0 - mnew);
        float p1 = __expf(a1 - mnew);
        float rs = p0 + p1;
        rs += __shfl_xor(rs, 1);
        rs += __shfl_xor(rs, 2);
        rs += __shfl_xor(rs, 4);
        rs += __shfl_xor(rs, 8);
        l_st[qi][rg] = l_st[qi][rg] * alpha + rs;
        m_st[qi][rg] = mnew;
        oacc[qi][0][rg] *= alpha;
        oacc[qi][1][rg] *= alpha;
        pw[rg] = packbf2(p0, p1);
      }
      unsigned* pbase = (unsigned*)Pw;
#pragma unroll
      for (int rg = 0; rg < 4; ++rg)
        pbase[((qd * 4 + rg) * PSTRIDE) / 2 + lm] = pw[rg];
      short8 pa = *(const short8*)&Pw[lm * PSTRIDE + qd * 8];
      oacc[qi][0] = __builtin_amdgcn_mfma_f32_16x16x32_bf16(pa, vf0, oacc[qi][0], 0, 0, 0);
      oacc[qi][1] = __builtin_amdgcn_mfma_f32_16x16x32_bf16(pa, vf1, oacc[qi][1], 0, 0, 0);
    }
  }

#pragma unroll
  for (int qi = 0; qi < 4; ++qi) {
#pragma unroll
    for (int rg = 0; rg < 4; ++rg) {
      const float inv = 1.0f / l_st[qi][rg];
      const int row = qw + qi * 16 + qd * 4 + rg;
      const size_t base = (rS + row) * HC_DIM + hb;
      float o0 = oacc[qi][0][rg] * inv * bf2f(g_ws[base + lm]);
      float o1 = oacc[qi][1][rg] * inv * bf2f(g_ws[base + 16 + lm]);
      ctx_ws[base + lm] = f2bf(o0);
      ctx_ws[base + 16 + lm] = f2bf(o1);
    }
  }
}

// ---------------------------------------------------------------------------
// Kernel E: out = ctx @ wo + bo -> fp32 [S,R,C]. Same v2 structure as proj:
// full-K LDS A-stage, one barrier, register-direct B, chunked XCD swizzle.
// ---------------------------------------------------------------------------
__global__ __launch_bounds__(256) void out_kernel(
    const unsigned short* __restrict__ ctx, const unsigned short* __restrict__ wot,
    const float* __restrict__ bo, float* __restrict__ out) {
  __shared__ __align__(16) unsigned short As[8 * 8 * 512];  // 64 KB

  const int bid = blockIdx.x;  // 1536 blocks; 1536 % 8 == 0
  const int orig = (bid & 7) * 192 + (bid >> 3);
  const int n0 = (orig & 1) << 7;  // n-tile fastest: 2 consecutive origs share A
  const int m0 = (orig >> 1) << 7;

  const int tid = threadIdx.x;
  const int wave = tid >> 6, lane = tid & 63;
  const int qd = lane >> 4, lm = lane & 15;
  const int wm = (wave & 1) * 64, wn = (wave >> 1) * 64;

  const int ga0 = wave * 2, ga1 = wave * 2 + 1;
  const unsigned short* agp0 = ctx + (size_t)(m0 + ga0 * 16 + lm) * 256 + qd * 8;
  const unsigned short* agp1 = ctx + (size_t)(m0 + ga1 * 16 + lm) * 256 + qd * 8;
#pragma unroll
  for (int c = 0; c < 8; ++c) {
    GLD_LDS16(agp0 + c * 32, &As[(size_t)(c * 8 + ga0) * 512]);
    GLD_LDS16(agp1 + c * 32, &As[(size_t)(c * 8 + ga1) * 512]);
  }

  const unsigned short* bp0 = wot + (size_t)(n0 + wn + 0 * 16 + lm) * 256 + qd * 8;
  const unsigned short* bp1 = wot + (size_t)(n0 + wn + 1 * 16 + lm) * 256 + qd * 8;
  const unsigned short* bp2 = wot + (size_t)(n0 + wn + 2 * 16 + lm) * 256 + qd * 8;
  const unsigned short* bp3 = wot + (size_t)(n0 + wn + 3 * 16 + lm) * 256 + qd * 8;

  floatx4 acc[4][4];
#pragma unroll
  for (int i = 0; i < 4; ++i)
#pragma unroll
    for (int j = 0; j < 4; ++j) acc[i][j] = (floatx4){0.f, 0.f, 0.f, 0.f};

  short8 bfr[2][4];
  bfr[0][0] = *(const short8*)(bp0);
  bfr[0][1] = *(const short8*)(bp1);
  bfr[0][2] = *(const short8*)(bp2);
  bfr[0][3] = *(const short8*)(bp3);

  __syncthreads();

#pragma unroll
  for (int c = 0; c < 8; ++c) {
    if (c < 7) {
      bfr[(c + 1) & 1][0] = *(const short8*)(bp0 + (c + 1) * 32);
      bfr[(c + 1) & 1][1] = *(const short8*)(bp1 + (c + 1) * 32);
      bfr[(c + 1) & 1][2] = *(const short8*)(bp2 + (c + 1) * 32);
      bfr[(c + 1) & 1][3] = *(const short8*)(bp3 + (c + 1) * 32);
    }
    short8 af[4];
#pragma unroll
    for (int t = 0; t < 4; ++t)
      af[t] = *(const short8*)((const char*)As +
                               (size_t)(c * 8 + wm / 16 + t) * 1024 + lane * 16);
#pragma unroll
    for (int tm = 0; tm < 4; ++tm)
#pragma unroll
      for (int tn = 0; tn < 4; ++tn)
        acc[tm][tn] = __builtin_amdgcn_mfma_f32_16x16x32_bf16(
            af[tm], bfr[c & 1][tn], acc[tm][tn], 0, 0, 0);
  }

#pragma unroll
  for (int tm = 0; tm < 4; ++tm)
#pragma unroll
    for (int tn = 0; tn < 4; ++tn)
#pragma unroll
      for (int rg = 0; rg < 4; ++rg) {
        const int m = m0 + wm + tm * 16 + qd * 4 + rg;
        const int n = n0 + wn + tn * 16 + lm;
        const int rr = m >> 8;   // r
        const int sc = m & 255;  // s
        out[((size_t)sc * R_DIM + rr) * C_DIM + n] = acc[tm][tn][rg] + bo[n];
      }
}

// ---------------------------------------------------------------------------
extern "C" void kernel_launch(void* const* d_in, const int* in_sizes, int n_in,
                              void* d_out, int out_size, void* d_ws, size_t ws_size,
                              hipStream_t stream) {
  const float* msa = (const float*)d_in[0];
  const float* mask = (const float*)d_in[1];
  const float* ln_g = (const float*)d_in[2];
  const float* ln_b = (const float*)d_in[3];
  const float* wq = (const float*)d_in[4];
  const float* wk = (const float*)d_in[5];
  const float* wv = (const float*)d_in[6];
  const float* wg = (const float*)d_in[7];
  const float* bg = (const float*)d_in[8];
  const float* wo = (const float*)d_in[9];
  const float* bo = (const float*)d_in[10];
  float* out = (float*)d_out;

  // workspace carve (~252.3 MB): Wt | x_ln (aliased as ctx) | q | k | v | g
  unsigned short* wt = (unsigned short*)d_ws;
  unsigned short* xln = wt + (size_t)1280 * 256;
  unsigned short* q_ws = xln + (size_t)M_DIM * 256;
  unsigned short* k_ws = q_ws + (size_t)M_DIM * 256;
  unsigned short* v_ws = k_ws + (size_t)M_DIM * 256;
  unsigned short* g_ws = v_ws + (size_t)M_DIM * 256;
  unsigned short* ctx_ws = xln;  // alias: x_ln dead after proj
  unsigned short* wot = wt + (size_t)1024 * 256;

  hipLaunchKernelGGL(wcat_kernel, dim3(20, 4), dim3(256), 0, stream,
                     wq, wk, wv, wg, wo, wt);
  hipLaunchKernelGGL(ln_kernel, dim3(M_DIM / 4), dim3(256), 0, stream,
                     msa, ln_g, ln_b, xln);
  hipLaunchKernelGGL(proj_kernel, dim3(8 * (M_DIM / 128)), dim3(256), 0, stream,
                     xln, wt, bg, q_ws, k_ws, v_ws, g_ws);
  hipLaunchKernelGGL(attn_kernel, dim3(R_DIM, H_DIM), dim3(256), 0, stream,
                     q_ws, k_ws, v_ws, g_ws, mask, ctx_ws);
  hipLaunchKernelGGL(out_kernel, dim3(2 * (M_DIM / 128)), dim3(256), 0, stream,
                     ctx_ws, wot, bo, out);
}